// Round 9
// baseline (442.526 us; speedup 1.0000x reference)
//
#include <hip/hip_runtime.h>

// Problem constants (match reference file)
constexpr int D = 128;       // node feature dim
constexpr int R = 64;        // edge feature dim (in = out)
constexpr int CAP = 64;      // per-dst bucket capacity (in-deg ~ Poisson(16))
constexpr int OVF_CAP = 65536;
constexpr int RT = 128;      // k_rel rows per block tile
constexpr int TPAD = 68;     // padded T-tile row stride: A banks 4*rg+4*k4 -> conflict-free

typedef float floatx4 __attribute__((ext_vector_type(4)));  // native vec for nontemporal builtins

static __device__ __forceinline__ float4 f4fma(float a, float4 w, float4 c) {
  c.x = fmaf(a, w.x, c.x); c.y = fmaf(a, w.y, c.y);
  c.z = fmaf(a, w.z, c.z); c.w = fmaf(a, w.w, c.w);
  return c;
}

static __device__ __forceinline__ void nt_store4(float4 v, float* p) {
  floatx4 q; q.x = v.x; q.y = v.y; q.z = v.z; q.w = v.w;
  __builtin_nontemporal_store(q, (floatx4*)p);
}

__global__ void k_init(int* deg_out, int* cursor, int* ovf_cnt, int n) {
  int i = blockIdx.x * blockDim.x + threadIdx.x;
  if (i < n) { deg_out[i] = 1; cursor[i] = 0; }  // deg_out=1: self loop
  if (i == 0) ovf_cnt[0] = 0;
}

// merged degree-count + bucket-fill: deg_in recovered as cursor+1 afterwards
__global__ void k_fill(const int* __restrict__ src, const int* __restrict__ dst,
                       int* deg_out, int* cursor, int* bucket,
                       int* ovf_cnt, int2* ovf, int e) {
  int i = blockIdx.x * blockDim.x + threadIdx.x;
  if (i >= e) return;
  int d = dst[i], s = src[i];
  atomicAdd(&deg_out[s], 1);
  int slot = atomicAdd(&cursor[d], 1);
  if (slot < CAP) bucket[(size_t)d * CAP + slot] = s;
  else {
    int oi = atomicAdd(ovf_cnt, 1);
    if (oi < OVF_CAP) ovf[oi] = make_int2(s, d);
  }
}

__global__ void k_norm(const int* __restrict__ deg_out, const int* __restrict__ cursor,
                       float* ns, float* nd, int n) {
  int i = blockIdx.x * blockDim.x + threadIdx.x;
  if (i < n) {
    ns[i] = rsqrtf((float)deg_out[i]);
    nd[i] = rsqrtf((float)(cursor[i] + 1));   // +1 = self loop
  }
}

// One 32-lane group per node; each lane holds a float4 (D=128 = 32*4).
// ns != null (layer1): agg[v] = x[v]*ns[v] + sum x[s]*ns[s]
// ns == null (layer2): input is pre-scaled h1' = h1*ns, so agg[v] = h'[v] + sum h'[s]
__global__ __launch_bounds__(256) void k_agg(const float* __restrict__ X,
                                             const float* __restrict__ ns,
                                             const int* __restrict__ cursor,
                                             const int* __restrict__ bucket,
                                             float* __restrict__ agg, int n) {
  int g = threadIdx.x >> 5, lane = threadIdx.x & 31;
  int v = blockIdx.x * 8 + g;
  if (v >= n) return;
  float4 acc;
  int cnt = min(cursor[v], CAP);
  const int* bk = bucket + (size_t)v * CAP;
  if (ns) {
    float4 xv = ((const float4*)(X + (size_t)v * D))[lane];
    float s = ns[v];
    acc.x = xv.x * s; acc.y = xv.y * s; acc.z = xv.z * s; acc.w = xv.w * s;
    int i = 0;
    for (; i + 4 <= cnt; i += 4) {
      int s0 = bk[i], s1 = bk[i + 1], s2 = bk[i + 2], s3 = bk[i + 3];
      float n0 = ns[s0], n1 = ns[s1], n2 = ns[s2], n3 = ns[s3];
      float4 x0 = ((const float4*)(X + (size_t)s0 * D))[lane];
      float4 x1 = ((const float4*)(X + (size_t)s1 * D))[lane];
      float4 x2 = ((const float4*)(X + (size_t)s2 * D))[lane];
      float4 x3 = ((const float4*)(X + (size_t)s3 * D))[lane];
      acc = f4fma(n0, x0, acc); acc = f4fma(n1, x1, acc);
      acc = f4fma(n2, x2, acc); acc = f4fma(n3, x3, acc);
    }
    for (; i < cnt; ++i) {
      int s0 = bk[i];
      float4 x0 = ((const float4*)(X + (size_t)s0 * D))[lane];
      acc = f4fma(ns[s0], x0, acc);
    }
  } else {
    acc = ((const float4*)(X + (size_t)v * D))[lane];
    int i = 0;
    for (; i + 4 <= cnt; i += 4) {
      int s0 = bk[i], s1 = bk[i + 1], s2 = bk[i + 2], s3 = bk[i + 3];
      float4 x0 = ((const float4*)(X + (size_t)s0 * D))[lane];
      float4 x1 = ((const float4*)(X + (size_t)s1 * D))[lane];
      float4 x2 = ((const float4*)(X + (size_t)s2 * D))[lane];
      float4 x3 = ((const float4*)(X + (size_t)s3 * D))[lane];
      acc.x += x0.x + x1.x + x2.x + x3.x;
      acc.y += x0.y + x1.y + x2.y + x3.y;
      acc.z += x0.z + x1.z + x2.z + x3.z;
      acc.w += x0.w + x1.w + x2.w + x3.w;
    }
    for (; i < cnt; ++i) {
      int s0 = bk[i];
      float4 x0 = ((const float4*)(X + (size_t)s0 * D))[lane];
      acc.x += x0.x; acc.y += x0.y; acc.z += x0.z; acc.w += x0.w;
    }
  }
  ((float4*)(agg + (size_t)v * D))[lane] = acc;
}

// Rare overflow edges (slot >= CAP): f32 atomics, normally zero work.
__global__ __launch_bounds__(128) void k_ovf(const float* __restrict__ X,
                                             const float* __restrict__ ns,
                                             const int* __restrict__ ovf_cnt,
                                             const int2* __restrict__ ovf,
                                             float* agg) {
  int m = min(ovf_cnt[0], OVF_CAP);
  int t = threadIdx.x;
  for (int i = blockIdx.x; i < m; i += gridDim.x) {
    int2 e = ovf[i];
    float s = ns ? ns[e.x] : 1.f;
    atomicAdd(&agg[(size_t)e.y * D + t], X[(size_t)e.x * D + t] * s);
  }
}

// out[r] = relu( (agg[r] @ W)*nd[r] + b ) * (post ? post[r] : 1). 64-row tile per block.
// post-scale folds next layer's norm_src into this epilogue (valid: post > 0).
__global__ __launch_bounds__(256) void k_gemm_relu(const float* __restrict__ A,
                                                   const float* __restrict__ ndv,
                                                   const float* __restrict__ W,
                                                   const float* __restrict__ bias,
                                                   const float* __restrict__ post,
                                                   float* __restrict__ out, int n) {
  __shared__ float Wl[D * D];  // 64 KiB
  int t = threadIdx.x;
  for (int i = t; i < (D * D) / 4; i += 256) ((float4*)Wl)[i] = ((const float4*)W)[i];
  __syncthreads();

  int ct = t & 15, rg = t >> 4;
  int c0 = ct << 2;            // cols c0..c0+3 and c0+64..c0+67
  int row0 = blockIdx.x * 64;

  float4 bb0 = *(const float4*)(bias + c0);
  float4 bb1 = *(const float4*)(bias + c0 + 64);

  int r[4]; const float4* Ap[4];
#pragma unroll
  for (int m = 0; m < 4; ++m) {
    r[m] = row0 + rg + 16 * m;
    int rc = (r[m] < n) ? r[m] : (n - 1);
    Ap[m] = (const float4*)(A + (size_t)rc * D);
  }

  float4 acc[4][2];
#pragma unroll
  for (int m = 0; m < 4; ++m) {
    acc[m][0] = make_float4(0.f, 0.f, 0.f, 0.f);
    acc[m][1] = make_float4(0.f, 0.f, 0.f, 0.f);
  }

#pragma unroll 8
  for (int k4 = 0; k4 < 32; ++k4) {
    float4 a0 = Ap[0][k4], a1 = Ap[1][k4], a2 = Ap[2][k4], a3 = Ap[3][k4];
    const float* wbase = Wl + (k4 << 9) + c0;
#pragma unroll
    for (int kk = 0; kk < 4; ++kk) {
      float4 w0 = *(const float4*)(wbase + (kk << 7));
      float4 w1 = *(const float4*)(wbase + (kk << 7) + 64);
      float e0 = (kk == 0) ? a0.x : (kk == 1) ? a0.y : (kk == 2) ? a0.z : a0.w;
      float e1 = (kk == 0) ? a1.x : (kk == 1) ? a1.y : (kk == 2) ? a1.z : a1.w;
      float e2 = (kk == 0) ? a2.x : (kk == 1) ? a2.y : (kk == 2) ? a2.z : a2.w;
      float e3 = (kk == 0) ? a3.x : (kk == 1) ? a3.y : (kk == 2) ? a3.z : a3.w;
      acc[0][0] = f4fma(e0, w0, acc[0][0]); acc[0][1] = f4fma(e0, w1, acc[0][1]);
      acc[1][0] = f4fma(e1, w0, acc[1][0]); acc[1][1] = f4fma(e1, w1, acc[1][1]);
      acc[2][0] = f4fma(e2, w0, acc[2][0]); acc[2][1] = f4fma(e2, w1, acc[2][1]);
      acc[3][0] = f4fma(e3, w0, acc[3][0]); acc[3][1] = f4fma(e3, w1, acc[3][1]);
    }
  }

#pragma unroll
  for (int m = 0; m < 4; ++m) {
    if (r[m] < n) {
      float ndr = ndv[r[m]];
      float ps = post ? post[r[m]] : 1.f;
      float4 o0, o1;
      o0.x = fmaxf(fmaf(acc[m][0].x, ndr, bb0.x), 0.f) * ps;
      o0.y = fmaxf(fmaf(acc[m][0].y, ndr, bb0.y), 0.f) * ps;
      o0.z = fmaxf(fmaf(acc[m][0].z, ndr, bb0.z), 0.f) * ps;
      o0.w = fmaxf(fmaf(acc[m][0].w, ndr, bb0.w), 0.f) * ps;
      o1.x = fmaxf(fmaf(acc[m][1].x, ndr, bb1.x), 0.f) * ps;
      o1.y = fmaxf(fmaf(acc[m][1].y, ndr, bb1.y), 0.f) * ps;
      o1.z = fmaxf(fmaf(acc[m][1].z, ndr, bb1.z), 0.f) * ps;
      o1.w = fmaxf(fmaf(acc[m][1].w, ndr, bb1.w), 0.f) * ps;
      *(float4*)(out + (size_t)r[m] * D + c0) = o0;
      *(float4*)(out + (size_t)r[m] * D + c0 + 64) = o1;
    }
  }
}

// e_h rows [0,E): text_h[row] @ relW + relb ; rows [E,E+N): relb (zero text).
// v6: 128-row tile, 4 rows x 8 cols per thread (8 col-threads x 32 row-groups).
// LDS reads per k4: 4 A b128 + 8 W b128 per 128 fma4 -> 0.75x traffic of 4x4;
// W staging amortized 2x. LDS 50.8KB -> 3 blocks/CU. nt stores (write-once out).
__global__ __launch_bounds__(256) void k_rel(const float* __restrict__ T,
                                             const float* __restrict__ Wr,
                                             const float* __restrict__ br,
                                             float* __restrict__ out,
                                             int e, int ntot) {
  __shared__ float Wl[R * R];      // 16 KiB
  __shared__ float Tl[RT * TPAD]; // 34 KiB
  int t = threadIdx.x;
  int tile = blockIdx.x;
  const float4 z4 = make_float4(0.f, 0.f, 0.f, 0.f);

  // issue T-tile loads first: 8 coalesced float4 loads per thread (128 rows x 16 f4)
  float4 pre[8];
#pragma unroll
  for (int j = 0; j < 8; ++j) {
    int q = t + 256 * j, rr = q >> 4, c4 = q & 15;
    int grow = tile * RT + rr;
    pre[j] = (grow < e) ? ((const float4*)T)[(size_t)grow * 16 + c4] : z4;
  }
  // W staging overlaps the T loads in flight
  for (int i = t; i < (R * R) / 4; i += 256) ((float4*)Wl)[i] = ((const float4*)Wr)[i];
#pragma unroll
  for (int j = 0; j < 8; ++j) {
    int q = t + 256 * j, rr = q >> 4, c4 = q & 15;
    *(float4*)&Tl[rr * TPAD + (c4 << 2)] = pre[j];
  }
  __syncthreads();

  int ct = t & 7, rg = t >> 3;   // 8 col-threads x 8 cols; 32 row-groups x 4 rows
  int c0 = ct << 3;
  float4 b0 = *(const float4*)(br + c0);
  float4 b1 = *(const float4*)(br + c0 + 4);

  float4 acc[4][2];
#pragma unroll
  for (int m = 0; m < 4; ++m) { acc[m][0] = b0; acc[m][1] = b1; }

#pragma unroll 4
  for (int k4 = 0; k4 < 16; ++k4) {
    float4 a0 = *(const float4*)&Tl[(rg     ) * TPAD + (k4 << 2)];
    float4 a1 = *(const float4*)&Tl[(rg + 32) * TPAD + (k4 << 2)];
    float4 a2 = *(const float4*)&Tl[(rg + 64) * TPAD + (k4 << 2)];
    float4 a3 = *(const float4*)&Tl[(rg + 96) * TPAD + (k4 << 2)];
    const float* wbase = Wl + (k4 << 8) + c0;
#pragma unroll
    for (int kk = 0; kk < 4; ++kk) {
      float4 w0 = *(const float4*)(wbase + (kk << 6));
      float4 w1 = *(const float4*)(wbase + (kk << 6) + 4);
      float e0 = (kk == 0) ? a0.x : (kk == 1) ? a0.y : (kk == 2) ? a0.z : a0.w;
      float e1 = (kk == 0) ? a1.x : (kk == 1) ? a1.y : (kk == 2) ? a1.z : a1.w;
      float e2 = (kk == 0) ? a2.x : (kk == 1) ? a2.y : (kk == 2) ? a2.z : a2.w;
      float e3 = (kk == 0) ? a3.x : (kk == 1) ? a3.y : (kk == 2) ? a3.z : a3.w;
      acc[0][0] = f4fma(e0, w0, acc[0][0]); acc[0][1] = f4fma(e0, w1, acc[0][1]);
      acc[1][0] = f4fma(e1, w0, acc[1][0]); acc[1][1] = f4fma(e1, w1, acc[1][1]);
      acc[2][0] = f4fma(e2, w0, acc[2][0]); acc[2][1] = f4fma(e2, w1, acc[2][1]);
      acc[3][0] = f4fma(e3, w0, acc[3][0]); acc[3][1] = f4fma(e3, w1, acc[3][1]);
    }
  }

  int base = tile * RT;
#pragma unroll
  for (int m = 0; m < 4; ++m) {
    int row = base + rg + 32 * m;
    if (row < ntot) {
      nt_store4(acc[m][0], out + (size_t)row * R + c0);
      nt_store4(acc[m][1], out + (size_t)row * R + c0 + 4);
    }
  }
}

extern "C" void kernel_launch(void* const* d_in, const int* in_sizes, int n_in,
                              void* d_out, int out_size, void* d_ws, size_t ws_size,
                              hipStream_t stream) {
  const int*   src  = (const int*)d_in[0];
  const int*   dst  = (const int*)d_in[1];
  const float* x    = (const float*)d_in[2];
  const float* text = (const float*)d_in[3];
  const float* W1   = (const float*)d_in[4];
  const float* b1   = (const float*)d_in[5];
  const float* W2   = (const float*)d_in[6];
  const float* b2   = (const float*)d_in[7];
  const float* relW = (const float*)d_in[8];
  const float* relb = (const float*)d_in[9];

  const int E = in_sizes[0];
  const int N = in_sizes[2] / D;

  float* outH = (float*)d_out;
  float* outE = outH + (size_t)N * D;

  // workspace carve-out (256B aligned)
  char* w = (char*)d_ws;
  auto alloc = [&](size_t bytes) -> void* {
    void* p = (void*)w;
    w += (bytes + 255) & ~(size_t)255;
    return p;
  };
  int*   deg_out  = (int*)alloc((size_t)N * 4);
  int*   cursor   = (int*)alloc((size_t)N * 4);
  float* norm_src = (float*)alloc((size_t)N * 4);
  float* norm_dst = (float*)alloc((size_t)N * 4);
  int*   ovf_cnt  = (int*)alloc(256);
  int2*  ovf      = (int2*)alloc((size_t)OVF_CAP * 8);
  int*   bucket   = (int*)alloc((size_t)N * CAP * 4);
  float* agg      = (float*)alloc((size_t)N * D * 4);

  int nbN = (N + 255) / 256;
  int nbE = (E + 255) / 256;

  k_init<<<nbN, 256, 0, stream>>>(deg_out, cursor, ovf_cnt, N);
  k_fill<<<nbE, 256, 0, stream>>>(src, dst, deg_out, cursor, bucket, ovf_cnt, ovf, E);
  k_norm<<<nbN, 256, 0, stream>>>(deg_out, cursor, norm_src, norm_dst, N);

  // layer 1: h1' = relu((agg1@W1)*nd + b1) * ns  -> outH   (ns folded for layer-2 gather)
  k_agg<<<(N + 7) / 8, 256, 0, stream>>>(x, norm_src, cursor, bucket, agg, N);
  k_ovf<<<64, 128, 0, stream>>>(x, norm_src, ovf_cnt, ovf, agg);
  k_gemm_relu<<<(N + 63) / 64, 256, 0, stream>>>(agg, norm_dst, W1, b1, norm_src, outH, N);

  // layer 2: gather pre-scaled h1' (no ns), h2 = relu((agg2@W2)*nd + b2) -> outH
  k_agg<<<(N + 7) / 8, 256, 0, stream>>>(outH, nullptr, cursor, bucket, agg, N);
  k_ovf<<<64, 128, 0, stream>>>(outH, nullptr, ovf_cnt, ovf, agg);
  k_gemm_relu<<<(N + 63) / 64, 256, 0, stream>>>(agg, norm_dst, W2, b2, nullptr, outH, N);

  // edge features
  int ntot = E + N;
  int nTiles = (ntot + RT - 1) / RT;
  k_rel<<<nTiles, 256, 0, stream>>>(text, relW, relb, outE, E, ntot);
}